// Round 1
// baseline (436.506 us; speedup 1.0000x reference)
//
#include <hip/hip_runtime.h>
#include <math.h>

#define BB 2
#define TT 512
#define UU 48
#define DD 512
#define HH 1024
#define KK 128

// ---------------- transpose: dst[C][R] = src[R][C], R,C multiples of 32 ----
__global__ __launch_bounds__(1024) void transpose_kernel(
    const float* __restrict__ src, float* __restrict__ dst, int R, int C) {
    __shared__ float tile[32][33];
    int bx = blockIdx.x * 32;  // col base in src
    int by = blockIdx.y * 32;  // row base in src
    int tx = threadIdx.x, ty = threadIdx.y;
    tile[ty][tx] = src[(size_t)(by + ty) * C + bx + tx];
    __syncthreads();
    dst[(size_t)(bx + ty) * R + by + tx] = tile[tx][ty];
}

// ---------------- generic fp32 GEMM: out[r][n] = sum_d A[r][d]*WT[d][n] (+bias)
// tile: 32 rows x 128 cols, kdim chunks of 64. 256 threads, 4x4 microtile.
__global__ __launch_bounds__(256) void gemm_kernel(
    const float* __restrict__ A,    // [nrows][kdim]
    const float* __restrict__ WT,   // [kdim][nout]
    const float* __restrict__ bias, // [nout] or nullptr
    float* __restrict__ out,        // [nrows][nout]
    int nrows, int kdim, int nout) {
    __shared__ __align__(16) float a_s[32 * 64];
    __shared__ __align__(16) float w_s[64 * 128];
    int tid = threadIdx.x;
    int ntr = nrows >> 5;
    int r0 = (blockIdx.x % ntr) * 32;
    int h0 = (blockIdx.x / ntr) * 128;
    int kg = tid & 31, tg = tid >> 5;
    int k4 = kg * 4, t4 = tg * 4;
    float acc[4][4] = {};
    int nch = kdim >> 6;
    for (int c = 0; c < nch; ++c) {
        int cb = c * 64;
#pragma unroll
        for (int i = 0; i < 8; ++i) {  // a fill: 2048 elems, coalesced
            int e = i * 256 + tid;
            int hh = e & 63, tt = e >> 6;
            a_s[tt * 64 + hh] = A[(size_t)(r0 + tt) * kdim + cb + hh];
        }
#pragma unroll
        for (int i = 0; i < 32; ++i) {  // w fill: 8192 elems, coalesced
            int e = i * 256 + tid;
            int k = e & 127, hh = e >> 7;
            w_s[hh * 128 + k] = WT[(size_t)(cb + hh) * nout + h0 + k];
        }
        __syncthreads();
#pragma unroll
        for (int hh = 0; hh < 64; hh += 4) {
            float aq[4][4], wq[4][4];
#pragma unroll
            for (int i = 0; i < 4; ++i)
                *(float4*)aq[i] = *(const float4*)&a_s[(t4 + i) * 64 + hh];
#pragma unroll
            for (int d = 0; d < 4; ++d)
                *(float4*)wq[d] = *(const float4*)&w_s[(hh + d) * 128 + k4];
#pragma unroll
            for (int d = 0; d < 4; ++d)
#pragma unroll
                for (int i = 0; i < 4; ++i)
#pragma unroll
                    for (int j = 0; j < 4; ++j)
                        acc[i][j] += aq[i][d] * wq[d][j];
        }
        __syncthreads();
    }
    float4 bb = make_float4(0.f, 0.f, 0.f, 0.f);
    if (bias) bb = *(const float4*)&bias[h0 + k4];
#pragma unroll
    for (int i = 0; i < 4; ++i) {
        float4 v;
        v.x = acc[i][0] + bb.x;
        v.y = acc[i][1] + bb.y;
        v.z = acc[i][2] + bb.z;
        v.w = acc[i][3] + bb.w;
        *(float4*)&out[(size_t)(r0 + t4 + i) * nout + h0 + k4] = v;
    }
}

// ---------------- img_seg_score: out[b][k][t] = (img[b,t,:]·conv_w[k,:]+cb[k])*mask[b,t]
__global__ __launch_bounds__(256) void seg_kernel(
    const float* __restrict__ img,   // [B*T][D]
    const float* __restrict__ cwT,   // [D][K]
    const float* __restrict__ cbias, // [K]
    const float* __restrict__ masks, // [B][T]
    float* __restrict__ out) {       // [B][K][T]
    __shared__ __align__(16) float a_s[32 * 64];
    __shared__ __align__(16) float w_s[64 * 128];
    int tid = threadIdx.x;
    int b = blockIdx.x >> 4;
    int t0 = (blockIdx.x & 15) * 32;
    const float* A = img + (size_t)b * TT * DD + (size_t)t0 * DD;
    int kg = tid & 31, tg = tid >> 5;
    int k4 = kg * 4, t4 = tg * 4;
    float acc[4][4] = {};
    for (int c = 0; c < 8; ++c) {
        int cb = c * 64;
#pragma unroll
        for (int i = 0; i < 8; ++i) {
            int e = i * 256 + tid;
            int hh = e & 63, tt = e >> 6;
            a_s[tt * 64 + hh] = A[(size_t)tt * DD + cb + hh];
        }
#pragma unroll
        for (int i = 0; i < 32; ++i) {
            int e = i * 256 + tid;
            int k = e & 127, hh = e >> 7;
            w_s[hh * 128 + k] = cwT[(size_t)(cb + hh) * KK + k];
        }
        __syncthreads();
#pragma unroll
        for (int hh = 0; hh < 64; hh += 4) {
            float aq[4][4], wq[4][4];
#pragma unroll
            for (int i = 0; i < 4; ++i)
                *(float4*)aq[i] = *(const float4*)&a_s[(t4 + i) * 64 + hh];
#pragma unroll
            for (int d = 0; d < 4; ++d)
                *(float4*)wq[d] = *(const float4*)&w_s[(hh + d) * 128 + k4];
#pragma unroll
            for (int d = 0; d < 4; ++d)
#pragma unroll
                for (int i = 0; i < 4; ++i)
#pragma unroll
                    for (int j = 0; j < 4; ++j)
                        acc[i][j] += aq[i][d] * wq[d][j];
        }
        __syncthreads();
    }
#pragma unroll
    for (int i = 0; i < 4; ++i) {
        float mk = masks[b * TT + t0 + t4 + i];
#pragma unroll
        for (int j = 0; j < 4; ++j) {
            out[(size_t)(b * KK + k4 + j) * TT + t0 + t4 + i] =
                (acc[i][j] + cbias[k4 + j]) * mk;
        }
    }
}

// ---------------- fused joint: tanh(img_bth + lab) @ W2T + b2 -> log_softmax
__global__ __launch_bounds__(256) void joint_kernel(
    const float* __restrict__ img_bth,  // [B*T][H]
    const float* __restrict__ lab,      // [B*U][H]  (b1 already folded in)
    const float* __restrict__ W2T,      // [H][K]
    const float* __restrict__ b2,       // [K]
    float* __restrict__ out) {          // [B*U*T][K]
    __shared__ __align__(16) float h_s[32 * 64];   // reused for row reductions
    __shared__ __align__(16) float w_s[64 * 128];  // reused as joint tile [32][128]
    int tid = threadIdx.x;
    int bid = blockIdx.x;
    int t0 = (bid & 15) * 32;
    int rest = bid >> 4;  // 0..95
    int u = rest % UU;
    int b = rest / UU;
    const float* imgrow = img_bth + ((size_t)b * TT + t0) * HH;
    const float* labrow = lab + ((size_t)b * UU + u) * HH;
    int kg = tid & 31, tg = tid >> 5;
    int k4 = kg * 4, t4 = tg * 4;
    float acc[4][4] = {};
    for (int c = 0; c < 16; ++c) {
        int cb = c * 64;
#pragma unroll
        for (int i = 0; i < 8; ++i) {  // h tile fill with fused tanh
            int e = i * 256 + tid;
            int hh = e & 63, tt = e >> 6;
            h_s[tt * 64 + hh] =
                tanhf(imgrow[(size_t)tt * HH + cb + hh] + labrow[cb + hh]);
        }
#pragma unroll
        for (int i = 0; i < 32; ++i) {
            int e = i * 256 + tid;
            int k = e & 127, hh = e >> 7;
            w_s[hh * 128 + k] = W2T[(size_t)(cb + hh) * KK + k];
        }
        __syncthreads();
#pragma unroll
        for (int hh = 0; hh < 64; hh += 4) {
            float aq[4][4], wq[4][4];
#pragma unroll
            for (int i = 0; i < 4; ++i)
                *(float4*)aq[i] = *(const float4*)&h_s[(t4 + i) * 64 + hh];
#pragma unroll
            for (int d = 0; d < 4; ++d)
                *(float4*)wq[d] = *(const float4*)&w_s[(hh + d) * 128 + k4];
#pragma unroll
            for (int d = 0; d < 4; ++d)
#pragma unroll
                for (int i = 0; i < 4; ++i)
#pragma unroll
                    for (int j = 0; j < 4; ++j)
                        acc[i][j] += aq[i][d] * wq[d][j];
        }
        __syncthreads();
    }
    // stash joint tile (with b2) into w_s, laid out [t][k]
    float4 bb = *(const float4*)&b2[k4];
#pragma unroll
    for (int i = 0; i < 4; ++i) {
        float4 v;
        v.x = acc[i][0] + bb.x;
        v.y = acc[i][1] + bb.y;
        v.z = acc[i][2] + bb.z;
        v.w = acc[i][3] + bb.w;
        *(float4*)&w_s[(t4 + i) * 128 + k4] = v;
    }
    __syncthreads();
    // log-softmax over k (128) per row t (32 rows, 8 threads/row)
    int r = tid >> 3, sub = tid & 7;
    float m = -INFINITY;
#pragma unroll
    for (int q = 0; q < 16; ++q) m = fmaxf(m, w_s[r * 128 + sub * 16 + q]);
    m = fmaxf(m, __shfl_xor(m, 1, 8));
    m = fmaxf(m, __shfl_xor(m, 2, 8));
    m = fmaxf(m, __shfl_xor(m, 4, 8));
    float s = 0.f;
#pragma unroll
    for (int q = 0; q < 16; ++q) s += expf(w_s[r * 128 + sub * 16 + q] - m);
    s += __shfl_xor(s, 1, 8);
    s += __shfl_xor(s, 2, 8);
    s += __shfl_xor(s, 4, 8);
    if (sub == 0) h_s[r] = m + logf(s);
    __syncthreads();
    float* orow = out + (((size_t)b * UU + u) * TT + t0) * KK;
#pragma unroll
    for (int i = 0; i < 16; ++i) {
        int e = i * 256 + tid;
        int k = e & 127, t = e >> 7;
        orow[(size_t)t * KK + k] = w_s[t * 128 + k] - h_s[t];
    }
}

extern "C" void kernel_launch(void* const* d_in, const int* in_sizes, int n_in,
                              void* d_out, int out_size, void* d_ws, size_t ws_size,
                              hipStream_t stream) {
    const float* img    = (const float*)d_in[0];  // (B,T,D)
    const float* labf   = (const float*)d_in[1];  // (B,U,D)
    const float* masks  = (const float*)d_in[2];  // (B,1,T)
    const float* W1     = (const float*)d_in[3];  // (H,2D)
    const float* b1     = (const float*)d_in[4];  // (H)
    const float* W2     = (const float*)d_in[5];  // (K,H)
    const float* b2     = (const float*)d_in[6];  // (K)
    const float* conv_w = (const float*)d_in[7];  // (K,D)
    const float* conv_b = (const float*)d_in[8];  // (K)
    float* out = (float*)d_out;
    float* ws = (float*)d_ws;

    // workspace layout (floats): total ~2.39M floats = 9.6 MB
    float* W1T  = ws;                       // [2D][H]  = 1024*1024
    float* W2T  = W1T + 1024 * 1024;        // [H][K]   = 1024*128
    float* cwT  = W2T + 1024 * 128;         // [D][K]   = 512*128
    float* imgH = cwT + 512 * 128;          // [B*T][H] = 1024*1024
    float* labH = imgH + 1024 * 1024;       // [B*U][H] = 96*1024

    dim3 tb(32, 32);
    transpose_kernel<<<dim3(2 * DD / 32, HH / 32), tb, 0, stream>>>(W1, W1T, HH, 2 * DD);
    transpose_kernel<<<dim3(HH / 32, KK / 32), tb, 0, stream>>>(W2, W2T, KK, HH);
    transpose_kernel<<<dim3(DD / 32, KK / 32), tb, 0, stream>>>(conv_w, cwT, KK, DD);

    // imgH[b*T+t][h] = img · Wi   (WiT = W1T rows 512..1023)
    gemm_kernel<<<(BB * TT / 32) * (HH / 128), 256, 0, stream>>>(
        img, W1T + (size_t)DD * HH, nullptr, imgH, BB * TT, DD, HH);
    // labH[b*U+u][h] = lab · Wl + b1   (WlT = W1T rows 0..511)
    gemm_kernel<<<(BB * UU / 32) * (HH / 128), 256, 0, stream>>>(
        labf, W1T, b1, labH, BB * UU, DD, HH);

    seg_kernel<<<BB * (TT / 32), 256, 0, stream>>>(img, cwT, conv_b, masks, out);

    joint_kernel<<<BB * UU * (TT / 32), 256, 0, stream>>>(
        imgH, labH, W2T, b2, out + (size_t)BB * KK * TT);
}

// Round 2
// 212.098 us; speedup vs baseline: 2.0580x; 2.0580x over previous
//
#include <hip/hip_runtime.h>
#include <math.h>

#define BB 2
#define TT 512
#define UU 48
#define DD 512
#define HH 1024
#define KK 128

typedef __bf16 bf16x8 __attribute__((ext_vector_type(8)));
typedef float floatx4 __attribute__((ext_vector_type(4)));

// ---------------- transpose: dst[C][R] = src[R][C], R,C multiples of 32 ----
__global__ __launch_bounds__(1024) void transpose_kernel(
    const float* __restrict__ src, float* __restrict__ dst, int R, int C) {
    __shared__ float tile[32][33];
    int bx = blockIdx.x * 32;
    int by = blockIdx.y * 32;
    int tx = threadIdx.x, ty = threadIdx.y;
    tile[ty][tx] = src[(size_t)(by + ty) * C + bx + tx];
    __syncthreads();
    dst[(size_t)(bx + ty) * R + by + tx] = tile[tx][ty];
}

// ---------------- W2 bf16 swizzle: W2s[(h>>3)*K*8 + k*8 + (h&7)] = bf16(W2[k][h])
__global__ __launch_bounds__(256) void prep_w2_kernel(
    const float* __restrict__ W2, __bf16* __restrict__ W2s) {
    int idx = blockIdx.x * 256 + threadIdx.x;  // 0..K*H-1
    int h = idx & (HH - 1);
    int k = idx >> 10;
    W2s[(size_t)(h >> 3) * (KK * 8) + k * 8 + (h & 7)] =
        (__bf16)W2[(size_t)k * HH + h];
}

// ---------------- generic fp32 GEMM: out[r][n] = sum_d A[r][d]*WT[d][n] (+bias)
__global__ __launch_bounds__(256) void gemm_kernel(
    const float* __restrict__ A, const float* __restrict__ WT,
    const float* __restrict__ bias, float* __restrict__ out,
    int nrows, int kdim, int nout) {
    __shared__ __align__(16) float a_s[32 * 64];
    __shared__ __align__(16) float w_s[64 * 128];
    int tid = threadIdx.x;
    int ntr = nrows >> 5;
    int r0 = (blockIdx.x % ntr) * 32;
    int h0 = (blockIdx.x / ntr) * 128;
    int kg = tid & 31, tg = tid >> 5;
    int k4 = kg * 4, t4 = tg * 4;
    float acc[4][4] = {};
    int nch = kdim >> 6;
    for (int c = 0; c < nch; ++c) {
        int cb = c * 64;
#pragma unroll
        for (int i = 0; i < 8; ++i) {
            int e = i * 256 + tid;
            int hh = e & 63, tt = e >> 6;
            a_s[tt * 64 + hh] = A[(size_t)(r0 + tt) * kdim + cb + hh];
        }
#pragma unroll
        for (int i = 0; i < 32; ++i) {
            int e = i * 256 + tid;
            int k = e & 127, hh = e >> 7;
            w_s[hh * 128 + k] = WT[(size_t)(cb + hh) * nout + h0 + k];
        }
        __syncthreads();
#pragma unroll
        for (int hh = 0; hh < 64; hh += 4) {
            float aq[4][4], wq[4][4];
#pragma unroll
            for (int i = 0; i < 4; ++i)
                *(float4*)aq[i] = *(const float4*)&a_s[(t4 + i) * 64 + hh];
#pragma unroll
            for (int d = 0; d < 4; ++d)
                *(float4*)wq[d] = *(const float4*)&w_s[(hh + d) * 128 + k4];
#pragma unroll
            for (int d = 0; d < 4; ++d)
#pragma unroll
                for (int i = 0; i < 4; ++i)
#pragma unroll
                    for (int j = 0; j < 4; ++j)
                        acc[i][j] += aq[i][d] * wq[d][j];
        }
        __syncthreads();
    }
    float4 bb = make_float4(0.f, 0.f, 0.f, 0.f);
    if (bias) bb = *(const float4*)&bias[h0 + k4];
#pragma unroll
    for (int i = 0; i < 4; ++i) {
        float4 v;
        v.x = acc[i][0] + bb.x;
        v.y = acc[i][1] + bb.y;
        v.z = acc[i][2] + bb.z;
        v.w = acc[i][3] + bb.w;
        *(float4*)&out[(size_t)(r0 + t4 + i) * nout + h0 + k4] = v;
    }
}

// ---------------- img_seg_score
__global__ __launch_bounds__(256) void seg_kernel(
    const float* __restrict__ img, const float* __restrict__ cwT,
    const float* __restrict__ cbias, const float* __restrict__ masks,
    float* __restrict__ out) {
    __shared__ __align__(16) float a_s[32 * 64];
    __shared__ __align__(16) float w_s[64 * 128];
    int tid = threadIdx.x;
    int b = blockIdx.x >> 4;
    int t0 = (blockIdx.x & 15) * 32;
    const float* A = img + (size_t)b * TT * DD + (size_t)t0 * DD;
    int kg = tid & 31, tg = tid >> 5;
    int k4 = kg * 4, t4 = tg * 4;
    float acc[4][4] = {};
    for (int c = 0; c < 8; ++c) {
        int cb = c * 64;
#pragma unroll
        for (int i = 0; i < 8; ++i) {
            int e = i * 256 + tid;
            int hh = e & 63, tt = e >> 6;
            a_s[tt * 64 + hh] = A[(size_t)tt * DD + cb + hh];
        }
#pragma unroll
        for (int i = 0; i < 32; ++i) {
            int e = i * 256 + tid;
            int k = e & 127, hh = e >> 7;
            w_s[hh * 128 + k] = cwT[(size_t)(cb + hh) * KK + k];
        }
        __syncthreads();
#pragma unroll
        for (int hh = 0; hh < 64; hh += 4) {
            float aq[4][4], wq[4][4];
#pragma unroll
            for (int i = 0; i < 4; ++i)
                *(float4*)aq[i] = *(const float4*)&a_s[(t4 + i) * 64 + hh];
#pragma unroll
            for (int d = 0; d < 4; ++d)
                *(float4*)wq[d] = *(const float4*)&w_s[(hh + d) * 128 + k4];
#pragma unroll
            for (int d = 0; d < 4; ++d)
#pragma unroll
                for (int i = 0; i < 4; ++i)
#pragma unroll
                    for (int j = 0; j < 4; ++j)
                        acc[i][j] += aq[i][d] * wq[d][j];
        }
        __syncthreads();
    }
#pragma unroll
    for (int i = 0; i < 4; ++i) {
        float mk = masks[b * TT + t0 + t4 + i];
#pragma unroll
        for (int j = 0; j < 4; ++j) {
            out[(size_t)(b * KK + k4 + j) * TT + t0 + t4 + i] =
                (acc[i][j] + cbias[k4 + j]) * mk;
        }
    }
}

__device__ __forceinline__ float fast_tanh(float x) {
    float e = __expf(2.0f * x);
    return __fdividef(e - 1.0f, e + 1.0f);
}

// ---------------- fused joint with bf16 MFMA
// h = tanh(imgH + labH) -> bf16 LDS; W2s swizzled bf16; mfma 16x16x32;
// epilogue: +b2, log_softmax over K=128, store.
__global__ __launch_bounds__(256) void joint_mfma_kernel(
    const float* __restrict__ img_bth,  // [B*T][H]
    const float* __restrict__ lab,      // [B*U][H] (b1 folded in)
    const __bf16* __restrict__ W2s,     // swizzled [H/8][K][8]
    const float* __restrict__ b2,
    float* __restrict__ out) {          // [B*U*T][K]
    __shared__ __align__(16) __bf16 h_s[32][72];   // pad to 72 (144B rows)
    __shared__ __align__(16) __bf16 w_s[64 * 128]; // swizzled chunk
    __shared__ __align__(16) float js[32 * 128];   // joint fp32 tile
    __shared__ float lse[32];
    int tid = threadIdx.x;
    int bid = blockIdx.x;
    int t0 = (bid & 15) * 32;
    int rest = bid >> 4;
    int u = rest % UU;
    int b = rest / UU;
    const float* imgrow = img_bth + ((size_t)b * TT + t0) * HH;
    const float* labrow = lab + ((size_t)b * UU + u) * HH;
    int lane = tid & 63, wv = tid >> 6;
    int m0 = (wv & 1) * 16;   // wave row base
    int n0 = (wv >> 1) * 64;  // wave col base
    floatx4 acc[4] = {{0.f, 0.f, 0.f, 0.f},
                      {0.f, 0.f, 0.f, 0.f},
                      {0.f, 0.f, 0.f, 0.f},
                      {0.f, 0.f, 0.f, 0.f}};
    int frow = tid >> 3;       // 0..31 (h fill row)
    int fk = (tid & 7) * 8;    // 0..56 (h fill col base)
    int arow = m0 + (lane & 15);
    int koff = (lane >> 4) * 8;
    for (int c = 0; c < HH / 64; ++c) {
        int cb = c * 64;
        // stage W2 chunk: contiguous 8192 bf16
        const __bf16* wgsrc = W2s + (size_t)cb * KK;
#pragma unroll
        for (int i = 0; i < 4; ++i) {
            int e = (i * 256 + tid) * 8;
            *(bf16x8*)&w_s[e] = *(const bf16x8*)&wgsrc[e];
        }
        // stage h tile: tanh(img + lab) -> bf16
        {
            const float* ip = &imgrow[(size_t)frow * HH + cb + fk];
            const float* lp = &labrow[cb + fk];
            float4 iv0 = *(const float4*)ip;
            float4 iv1 = *(const float4*)(ip + 4);
            float4 lv0 = *(const float4*)lp;
            float4 lv1 = *(const float4*)(lp + 4);
            bf16x8 hv;
            hv[0] = (__bf16)fast_tanh(iv0.x + lv0.x);
            hv[1] = (__bf16)fast_tanh(iv0.y + lv0.y);
            hv[2] = (__bf16)fast_tanh(iv0.z + lv0.z);
            hv[3] = (__bf16)fast_tanh(iv0.w + lv0.w);
            hv[4] = (__bf16)fast_tanh(iv1.x + lv1.x);
            hv[5] = (__bf16)fast_tanh(iv1.y + lv1.y);
            hv[6] = (__bf16)fast_tanh(iv1.z + lv1.z);
            hv[7] = (__bf16)fast_tanh(iv1.w + lv1.w);
            *(bf16x8*)&h_s[frow][fk] = hv;
        }
        __syncthreads();
#pragma unroll
        for (int kt = 0; kt < 2; ++kt) {
            bf16x8 afrag = *(const bf16x8*)&h_s[arow][kt * 32 + koff];
#pragma unroll
            for (int nt = 0; nt < 4; ++nt) {
                const __bf16* bp =
                    &w_s[((kt * 4 + (lane >> 4)) * 128 + n0 + nt * 16 +
                          (lane & 15)) * 8];
                bf16x8 bfrag = *(const bf16x8*)bp;
                acc[nt] = __builtin_amdgcn_mfma_f32_16x16x32_bf16(
                    afrag, bfrag, acc[nt], 0, 0, 0);
            }
        }
        __syncthreads();
    }
    // write acc -> js with +b2  (C/D: col=lane&15, row=(lane>>4)*4+reg)
    int col = lane & 15, rbase = (lane >> 4) * 4;
#pragma unroll
    for (int nt = 0; nt < 4; ++nt) {
        int n = n0 + nt * 16 + col;
        float bias = b2[n];
#pragma unroll
        for (int r = 0; r < 4; ++r)
            js[(m0 + rbase + r) * 128 + n] = acc[nt][r] + bias;
    }
    __syncthreads();
    // log-softmax over k (128) per row (32 rows, 8 threads/row)
    {
        int r = tid >> 3, sub = tid & 7;
        float m = -INFINITY;
#pragma unroll
        for (int q = 0; q < 16; ++q) m = fmaxf(m, js[r * 128 + sub * 16 + q]);
        m = fmaxf(m, __shfl_xor(m, 1, 8));
        m = fmaxf(m, __shfl_xor(m, 2, 8));
        m = fmaxf(m, __shfl_xor(m, 4, 8));
        float s = 0.f;
#pragma unroll
        for (int q = 0; q < 16; ++q) s += __expf(js[r * 128 + sub * 16 + q] - m);
        s += __shfl_xor(s, 1, 8);
        s += __shfl_xor(s, 2, 8);
        s += __shfl_xor(s, 4, 8);
        if (sub == 0) lse[r] = m + __logf(s);
    }
    __syncthreads();
    float* orow = out + (((size_t)b * UU + u) * TT + t0) * KK;
    int ocol = (tid & 31) * 4;
    int trow = tid >> 5;
#pragma unroll
    for (int p = 0; p < 4; ++p) {
        int t = trow + p * 8;
        float4 v = *(float4*)&js[t * 128 + ocol];
        float l = lse[t];
        v.x -= l; v.y -= l; v.z -= l; v.w -= l;
        *(float4*)&orow[(size_t)t * KK + ocol] = v;
    }
}

extern "C" void kernel_launch(void* const* d_in, const int* in_sizes, int n_in,
                              void* d_out, int out_size, void* d_ws, size_t ws_size,
                              hipStream_t stream) {
    const float* img    = (const float*)d_in[0];
    const float* labf   = (const float*)d_in[1];
    const float* masks  = (const float*)d_in[2];
    const float* W1     = (const float*)d_in[3];
    const float* b1     = (const float*)d_in[4];
    const float* W2     = (const float*)d_in[5];
    const float* b2     = (const float*)d_in[6];
    const float* conv_w = (const float*)d_in[7];
    const float* conv_b = (const float*)d_in[8];
    float* out = (float*)d_out;
    float* ws = (float*)d_ws;

    // workspace layout
    float* W1T  = ws;                        // [2D][H] = 1024*1024
    float* cwT  = W1T + 1024 * 1024;         // [D][K]  = 512*128
    float* imgH = cwT + 512 * 128;           // [B*T][H] = 1024*1024
    float* labH = imgH + 1024 * 1024;        // [B*U][H] = 96*1024
    __bf16* W2s = (__bf16*)(labH + 96 * 1024);  // [H/8][K][8] = 131072 bf16

    dim3 tb(32, 32);
    transpose_kernel<<<dim3(2 * DD / 32, HH / 32), tb, 0, stream>>>(W1, W1T, HH, 2 * DD);
    transpose_kernel<<<dim3(DD / 32, KK / 32), tb, 0, stream>>>(conv_w, cwT, KK, DD);
    prep_w2_kernel<<<KK * HH / 256, 256, 0, stream>>>(W2, W2s);

    gemm_kernel<<<(BB * TT / 32) * (HH / 128), 256, 0, stream>>>(
        img, W1T + (size_t)DD * HH, nullptr, imgH, BB * TT, DD, HH);
    gemm_kernel<<<(BB * UU / 32) * (HH / 128), 256, 0, stream>>>(
        labf, W1T, b1, labH, BB * UU, DD, HH);

    seg_kernel<<<BB * (TT / 32), 256, 0, stream>>>(img, cwT, conv_b, masks, out);

    joint_mfma_kernel<<<BB * UU * (TT / 32), 256, 0, stream>>>(
        imgH, labH, W2s, b2, out + (size_t)BB * KK * TT);
}

// Round 3
// 144.597 us; speedup vs baseline: 3.0188x; 1.4668x over previous
//
#include <hip/hip_runtime.h>
#include <math.h>

#define BB 2
#define TT 512
#define UU 48
#define DD 512
#define HH 1024
#define KK 128

typedef __bf16 bf16x8 __attribute__((ext_vector_type(8)));
typedef float floatx4 __attribute__((ext_vector_type(4)));

__device__ __forceinline__ float fast_tanh(float x) {
    float e = __expf(2.0f * x);
    return __fdividef(e - 1.0f, e + 1.0f);
}

// ---------------- prep: bf16 casts + MFMA-B swizzles, one pass ----------------
// swizzle layout: Ws[(k>>3)*nout*8 + n*8 + (k&7)] = W[n][k]  (contraction dim k)
__global__ __launch_bounds__(256) void prep_kernel(
    const float* __restrict__ img, const float* __restrict__ labf,
    const float* __restrict__ W1, const float* __restrict__ W2,
    const float* __restrict__ conv_w,
    __bf16* __restrict__ img_b, __bf16* __restrict__ lab_b,
    __bf16* __restrict__ W1s_l, __bf16* __restrict__ W1s_i,
    __bf16* __restrict__ W2s, __bf16* __restrict__ cws) {
    int idx = blockIdx.x * 256 + threadIdx.x;
    if (idx < 524288) {                       // img -> bf16
        img_b[idx] = (__bf16)img[idx];
    } else if (idx < 573440) {                // lab -> bf16
        int i = idx - 524288;
        lab_b[i] = (__bf16)labf[i];
    } else if (idx < 1622016) {               // W1 halves swizzled
        int i = idx - 573440;
        int half = i >> 19;                   // 0: Wl, 1: Wi
        int rr = i & 524287;
        int h = rr >> 9, d = rr & 511;
        float v = W1[(size_t)h * 1024 + half * 512 + d];
        __bf16* dst = half ? W1s_i : W1s_l;
        dst[(d >> 3) * (HH * 8) + h * 8 + (d & 7)] = (__bf16)v;
    } else if (idx < 1753088) {               // W2 swizzled
        int i = idx - 1622016;
        int k = i >> 10, h = i & 1023;
        W2s[(h >> 3) * (KK * 8) + k * 8 + (h & 7)] = (__bf16)W2[i];
    } else if (idx < 1818624) {               // conv_w swizzled
        int i = idx - 1753088;
        int k = i >> 9, d = i & 511;
        cws[(d >> 3) * (KK * 8) + k * 8 + (d & 7)] = (__bf16)conv_w[i];
    }
}

// ---------------- mid: imgH / labH / seg GEMMs fused into one dispatch -------
// region 0 (bid<256):  imgH[r][n] = img_b[r]·Wi          (M=1024,N=1024,K=512)
// region 1 (bid<280):  labH[r][n] = lab_b[r]·Wl + b1     (M=96,  N=1024,K=512)
// region 2 (bid<312):  seg[b][k][t] = (img_b·cw + cb)*mask (M=1024,N=128,K=512)
__global__ __launch_bounds__(256) void mid_kernel(
    const __bf16* __restrict__ img_b, const __bf16* __restrict__ lab_b,
    const __bf16* __restrict__ W1s_l, const __bf16* __restrict__ W1s_i,
    const __bf16* __restrict__ cws,
    const float* __restrict__ b1, const float* __restrict__ conv_b,
    const float* __restrict__ masks,
    float* __restrict__ imgH, float* __restrict__ labH,
    float* __restrict__ seg_out) {
    __shared__ __align__(16) __bf16 a_s[32][72];
    __shared__ __align__(16) __bf16 w_s[8192];
    int bid = blockIdx.x;
    int tid = threadIdx.x;
    const __bf16* A;
    const __bf16* Ws;
    int r0, n0b, nout, region;
    if (bid < 256) {
        region = 0; A = img_b; Ws = W1s_i;
        r0 = (bid & 31) * 32; n0b = (bid >> 5) * 128; nout = HH;
    } else if (bid < 280) {
        region = 1; A = lab_b; Ws = W1s_l;
        int i = bid - 256; r0 = (i % 3) * 32; n0b = (i / 3) * 128; nout = HH;
    } else {
        region = 2; A = img_b; Ws = cws;
        r0 = (bid - 280) * 32; n0b = 0; nout = KK;
    }
    int lane = tid & 63, wv = tid >> 6;
    int m0 = (wv & 1) * 16, n0w = (wv >> 1) * 64;
    int q = lane >> 4, r = lane & 15;
    int arow = tid >> 3, acol = (tid & 7) * 8;
    floatx4 acc[4] = {};
    for (int c = 0; c < 8; ++c) {
        int cb = c * 64;
        // A tile: 32x64 bf16, one 16B store/thread
        *(bf16x8*)&a_s[arow][acol] =
            *(const bf16x8*)&A[(size_t)(r0 + arow) * DD + cb + acol];
        // W chunk: 64x128 swizzled, 4x16B per thread, coalesced
        int cg = cb >> 3;
#pragma unroll
        for (int i2 = 0; i2 < 4; ++i2) {
            int uu = i2 * 256 + tid;
            int g = uu >> 7, j = uu & 127;
            *(bf16x8*)&w_s[uu * 8] =
                *(const bf16x8*)&Ws[((size_t)(cg + g) * nout + n0b + j) * 8];
        }
        __syncthreads();
#pragma unroll
        for (int kt = 0; kt < 2; ++kt) {
            bf16x8 af = *(const bf16x8*)&a_s[m0 + r][kt * 32 + q * 8];
#pragma unroll
            for (int nt = 0; nt < 4; ++nt) {
                bf16x8 bf = *(const bf16x8*)
                    &w_s[((kt * 4 + q) * 128 + n0w + nt * 16 + r) * 8];
                acc[nt] = __builtin_amdgcn_mfma_f32_16x16x32_bf16(
                    af, bf, acc[nt], 0, 0, 0);
            }
        }
        __syncthreads();
    }
    // epilogue (C/D: col=lane&15, row=(lane>>4)*4+reg)
    if (region == 0) {
#pragma unroll
        for (int nt = 0; nt < 4; ++nt) {
            int n = n0b + n0w + nt * 16 + r;
#pragma unroll
            for (int rr = 0; rr < 4; ++rr)
                imgH[(size_t)(r0 + m0 + 4 * q + rr) * HH + n] = acc[nt][rr];
        }
    } else if (region == 1) {
#pragma unroll
        for (int nt = 0; nt < 4; ++nt) {
            int n = n0b + n0w + nt * 16 + r;
            float bv = b1[n];
#pragma unroll
            for (int rr = 0; rr < 4; ++rr)
                labH[(size_t)(r0 + m0 + 4 * q + rr) * HH + n] = acc[nt][rr] + bv;
        }
    } else {
#pragma unroll
        for (int nt = 0; nt < 4; ++nt) {
            int k = n0w + nt * 16 + r;
            float bv = conv_b[k];
#pragma unroll
            for (int rr = 0; rr < 4; ++rr) {
                int row = r0 + m0 + 4 * q + rr;
                int b = row >> 9, t = row & 511;
                seg_out[((size_t)b * KK + k) * TT + t] =
                    (acc[nt][rr] + bv) * masks[row];
            }
        }
    }
}

// ---------------- joint: 64-row tile, wave owns full K=128, in-reg softmax --
__global__ __launch_bounds__(256) void joint_kernel2(
    const float* __restrict__ imgH,  // [B*T][H]
    const float* __restrict__ labH,  // [B*U][H] (b1 folded)
    const __bf16* __restrict__ W2s,  // swizzled
    const float* __restrict__ b2,
    float* __restrict__ out) {       // [B*U*T][K]
    __shared__ __align__(16) __bf16 h_s[64][72];
    __shared__ __align__(16) __bf16 w_s[8192];
    int tid = threadIdx.x;
    int bid = blockIdx.x;
    int t0 = (bid & 7) * 64;
    int rest = bid >> 3;
    int u = rest % UU;
    int b = rest / UU;
    const float* imgrow = imgH + ((size_t)b * TT + t0) * HH;
    const float* labrow = labH + ((size_t)b * UU + u) * HH;
    int lane = tid & 63, wv = tid >> 6;
    int m0 = wv * 16;
    int q = lane >> 4, r = lane & 15;
    int srow2 = (tid >> 3) * 2;
    int scol = (tid & 7) * 8;
    floatx4 acc[8] = {};
    for (int c = 0; c < 16; ++c) {
        int cb = c * 64;
        // W2 chunk: contiguous 16 KB
        const __bf16* wsrc = W2s + (size_t)cb * KK;
#pragma unroll
        for (int i2 = 0; i2 < 4; ++i2) {
            int e = (i2 * 256 + tid) * 8;
            *(bf16x8*)&w_s[e] = *(const bf16x8*)&wsrc[e];
        }
        // h tile: 2 rows x 8 cols per thread, lab loaded once
        float lv[8];
        *(float4*)&lv[0] = *(const float4*)&labrow[cb + scol];
        *(float4*)&lv[4] = *(const float4*)&labrow[cb + scol + 4];
#pragma unroll
        for (int rr = 0; rr < 2; ++rr) {
            const float* ip = &imgrow[(size_t)(srow2 + rr) * HH + cb + scol];
            float4 iv0 = *(const float4*)ip;
            float4 iv1 = *(const float4*)(ip + 4);
            bf16x8 hv;
            hv[0] = (__bf16)fast_tanh(iv0.x + lv[0]);
            hv[1] = (__bf16)fast_tanh(iv0.y + lv[1]);
            hv[2] = (__bf16)fast_tanh(iv0.z + lv[2]);
            hv[3] = (__bf16)fast_tanh(iv0.w + lv[3]);
            hv[4] = (__bf16)fast_tanh(iv1.x + lv[4]);
            hv[5] = (__bf16)fast_tanh(iv1.y + lv[5]);
            hv[6] = (__bf16)fast_tanh(iv1.z + lv[6]);
            hv[7] = (__bf16)fast_tanh(iv1.w + lv[7]);
            *(bf16x8*)&h_s[srow2 + rr][scol] = hv;
        }
        __syncthreads();
#pragma unroll
        for (int kt = 0; kt < 2; ++kt) {
            bf16x8 af = *(const bf16x8*)&h_s[m0 + r][kt * 32 + q * 8];
#pragma unroll
            for (int nt = 0; nt < 8; ++nt) {
                bf16x8 bf = *(const bf16x8*)
                    &w_s[((kt * 4 + q) * 128 + nt * 16 + r) * 8];
                acc[nt] = __builtin_amdgcn_mfma_f32_16x16x32_bf16(
                    af, bf, acc[nt], 0, 0, 0);
            }
        }
        __syncthreads();
    }
    // epilogue: +b2, log-softmax over 128 cols held by this 16-lane group
    float b2v[8];
#pragma unroll
    for (int nt = 0; nt < 8; ++nt) b2v[nt] = b2[nt * 16 + r];
    float* orow = out + (((size_t)b * UU + u) * TT + t0 + m0) * KK;
#pragma unroll
    for (int rr = 0; rr < 4; ++rr) {
        float v[8];
        float mx = -INFINITY;
#pragma unroll
        for (int nt = 0; nt < 8; ++nt) {
            v[nt] = acc[nt][rr] + b2v[nt];
            mx = fmaxf(mx, v[nt]);
        }
        mx = fmaxf(mx, __shfl_xor(mx, 1, 16));
        mx = fmaxf(mx, __shfl_xor(mx, 2, 16));
        mx = fmaxf(mx, __shfl_xor(mx, 4, 16));
        mx = fmaxf(mx, __shfl_xor(mx, 8, 16));
        float s = 0.f;
#pragma unroll
        for (int nt = 0; nt < 8; ++nt) s += __expf(v[nt] - mx);
        s += __shfl_xor(s, 1, 16);
        s += __shfl_xor(s, 2, 16);
        s += __shfl_xor(s, 4, 16);
        s += __shfl_xor(s, 8, 16);
        float lse = mx + __logf(s);
        int row = 4 * q + rr;
#pragma unroll
        for (int nt = 0; nt < 8; ++nt)
            orow[(size_t)row * KK + nt * 16 + r] = v[nt] - lse;
    }
}

extern "C" void kernel_launch(void* const* d_in, const int* in_sizes, int n_in,
                              void* d_out, int out_size, void* d_ws, size_t ws_size,
                              hipStream_t stream) {
    const float* img    = (const float*)d_in[0];
    const float* labf   = (const float*)d_in[1];
    const float* masks  = (const float*)d_in[2];
    const float* W1     = (const float*)d_in[3];
    const float* b1     = (const float*)d_in[4];
    const float* W2     = (const float*)d_in[5];
    const float* b2     = (const float*)d_in[6];
    const float* conv_w = (const float*)d_in[7];
    const float* conv_b = (const float*)d_in[8];
    float* out = (float*)d_out;
    float* ws = (float*)d_ws;

    // workspace: fp32 first, then bf16 region (all 16B aligned)
    float* imgH = ws;                              // [1024][1024]
    float* labH = imgH + 1024 * 1024;              // [96][1024]
    __bf16* base  = (__bf16*)(labH + 96 * 1024);
    __bf16* img_b = base;                          // 524288
    __bf16* lab_b = img_b + 524288;                // 49152
    __bf16* W1s_l = lab_b + 49152;                 // 524288
    __bf16* W1s_i = W1s_l + 524288;                // 524288
    __bf16* W2s   = W1s_i + 524288;                // 131072
    __bf16* cws   = W2s + 131072;                  // 65536

    prep_kernel<<<7104, 256, 0, stream>>>(img, labf, W1, W2, conv_w,
                                          img_b, lab_b, W1s_l, W1s_i, W2s, cws);
    mid_kernel<<<312, 256, 0, stream>>>(img_b, lab_b, W1s_l, W1s_i, cws,
                                        b1, conv_b, masks, imgH, labH, out);
    joint_kernel2<<<768, 256, 0, stream>>>(imgH, labH, W2s, b2,
                                           out + (size_t)BB * KK * TT);
}